// Round 5
// baseline (802.202 us; speedup 1.0000x reference)
//
#include <hip/hip_runtime.h>
#include <hip/hip_bf16.h>
#include <hip/hip_fp16.h>

#define VOCAB 32000
#define H 256
#define B 4
#define S 512

typedef _Float16 f16x8 __attribute__((ext_vector_type(8)));
typedef short s16x8 __attribute__((ext_vector_type(8)));
typedef float f32x4 __attribute__((ext_vector_type(4)));

__device__ __forceinline__ float tanh_fast(float x) {
    // tanh(x) = 1 - 2/(exp(2x)+1); exp via exp2. Saturates correctly for |x| large.
    float e = exp2f(x * 2.885390081777927f);   // exp(2x)
    return 1.0f - 2.0f * __builtin_amdgcn_rcpf(e + 1.0f);
}

// ---------------------------------------------------------------------------
// K0: Wo (256 x 32000) f32  ->  WoT (32000 x 256) bf16   (MFMA B-frag friendly)
// ---------------------------------------------------------------------------
__global__ void k_wot(const float* __restrict__ Wo, __hip_bfloat16* __restrict__ WoT) {
    __shared__ float tile[64][65];
    int n0 = blockIdx.x * 64, k0 = blockIdx.y * 64;
    int tx = threadIdx.x & 63, ty = threadIdx.x >> 6;
#pragma unroll
    for (int i = 0; i < 16; ++i) {
        int k = ty * 16 + i;
        tile[k][tx] = Wo[(size_t)(k0 + k) * VOCAB + n0 + tx];
    }
    __syncthreads();
#pragma unroll
    for (int i = 0; i < 16; ++i) {
        int n = ty * 16 + i;
        WoT[(size_t)(n0 + n) * H + k0 + tx] = __float2bfloat16(tile[tx][n]);
    }
}

// ---------------------------------------------------------------------------
// K1: Ew[t][j][b] = sum_i embed[x[b][t]][i] * Wi[i][j] + bi[j] + bh[j]   (f32)
// ---------------------------------------------------------------------------
__global__ void k_eprep(const int* __restrict__ x, const float* __restrict__ embed,
                        const float* __restrict__ Wi, const float* __restrict__ bi,
                        const float* __restrict__ bh, float* __restrict__ Ew) {
    int t = blockIdx.x, j = threadIdx.x;
    __shared__ float es[B][H];
    __shared__ int xs[B];
    if (j < B) xs[j] = x[j * S + t];
    __syncthreads();
    for (int b = 0; b < B; ++b) es[b][j] = embed[(size_t)xs[b] * H + j];
    float bias = bi[j] + bh[j];
    float a0 = bias, a1 = bias, a2 = bias, a3 = bias;
    __syncthreads();
    for (int i = 0; i < H; ++i) {
        float w = Wi[i * H + j];
        a0 += es[0][i] * w; a1 += es[1][i] * w;
        a2 += es[2][i] * w; a3 += es[3][i] * w;
    }
    f32x4 v; v[0] = a0; v[1] = a1; v[2] = a2; v[3] = a3;
    *(f32x4*)&Ew[(t * H + j) * 4] = v;
}

// ---------------------------------------------------------------------------
// K2 v5: serial RNN scan. Grid = 256 blocks: block 0 is the real scan (sole
// writer); blocks 1-255 run the identical compute (no global stores) as a
// DVFS/occupancy pad. Theory (R4 post-mortem): with 1/256 CUs busy the clock
// governor holds a low SCLK; the measured step (~725ns) matches the cycle
// model (~930cy) only at ~1.3GHz. Padding the chip keeps every CU busy with
// the same-duration work; dispatch time == block 0's time at whatever clock
// results. Downside bounded to contention noise on L2-resident Ew/Wh.
//  - body == R3's best (371us): pitch 258, shfl redistribute, immediate
//    stores, depth-2 Ew prefetch, 1 barrier/step.  R4's delayed-store
//    rotation REVERTED (+31us regression).
// ---------------------------------------------------------------------------
__global__ __launch_bounds__(256, 1) void k_rnn(const float* __restrict__ Ew,
                                                const float* __restrict__ Wh,
                                                _Float16* __restrict__ enc16,
                                                float* __restrict__ out_tail) {
    const int tid = threadIdx.x;
    const int w = tid >> 6;
    const int l = tid & 63;
    const int lg = l >> 4;
    const int ll = l & 15;
    const bool writer = (blockIdx.x == 0);

    __shared__ _Float16 hbuf[2][4][258];
    for (int idx = tid; idx < 2 * 4 * 258; idx += 256) (&hbuf[0][0][0])[idx] = (_Float16)0.f;

    // Wh B-fragments resident in VGPRs: B[k][n], lane: col=ll, k=lg*8+e (+32*kk)
    f16x8 Bf[4][8];
#pragma unroll
    for (int nt = 0; nt < 4; ++nt) {
        int col = w * 64 + nt * 16 + ll;
#pragma unroll
        for (int kk = 0; kk < 8; ++kk) {
            int kb = kk * 32 + lg * 8;
            f16x8 v;
#pragma unroll
            for (int e = 0; e < 8; ++e) v[e] = (_Float16)Wh[(kb + e) * H + col];
            Bf[nt][kk] = v;
        }
    }
    __syncthreads();

    // Ew depth-2 register prefetch
    f32x4 eacc[2][4];
#pragma unroll
    for (int d = 0; d < 2; ++d)
#pragma unroll
        for (int nt = 0; nt < 4; ++nt) {
            int j = w * 64 + nt * 16 + ll;
            eacc[d][nt] = *(const f32x4*)&Ew[(d * H + j) * 4];
        }

    const int jcol = w * 64 + lg * 16 + ll;   // this lane's output column

    for (int t0 = 0; t0 < S; t0 += 2) {
#pragma unroll
        for (int u = 0; u < 2; ++u) {
            const int t = t0 + u;
            const int cur = u, nxt = u ^ 1;

            f16x8 Af[8];
#pragma unroll
            for (int kk = 0; kk < 8; ++kk)
                Af[kk] = *(const f16x8*)&hbuf[cur][l & 3][kk * 32 + lg * 8];

            f32x4 acc[4];
#pragma unroll
            for (int nt = 0; nt < 4; ++nt) acc[nt] = eacc[u][nt];

            {   // prefetch t+2
                int tp = (t + 2 < S) ? t + 2 : S - 1;
#pragma unroll
                for (int nt = 0; nt < 4; ++nt) {
                    int j = w * 64 + nt * 16 + ll;
                    eacc[u][nt] = *(const f32x4*)&Ew[(tp * H + j) * 4];
                }
            }

#pragma unroll
            for (int kk = 0; kk < 8; ++kk)
#pragma unroll
                for (int nt = 0; nt < 4; ++nt)
                    acc[nt] = __builtin_amdgcn_mfma_f32_16x16x32_f16(Af[kk], Bf[nt][kk], acc[nt], 0, 0, 0);

            // redistribute: lane l gets (tile nt=lg, col ll), rows r=0..3
            float v[4];
#pragma unroll
            for (int nt = 0; nt < 4; ++nt)
#pragma unroll
                for (int r = 0; r < 4; ++r) {
                    float tv = __shfl(acc[nt][r], ll);
                    if (lg == nt) v[r] = tv;
                }

#pragma unroll
            for (int r = 0; r < 4; ++r) {
                float hf = tanh_fast(v[r]);
                _Float16 h16 = (_Float16)hf;
                hbuf[nxt][r][jcol] = h16;
                if (writer) enc16[(r * S + t) * H + jcol] = h16;   // fire-and-forget
            }
            if (writer && t == S - 1) {
#pragma unroll
                for (int r = 0; r < 4; ++r)
                    out_tail[r * H + jcol] = tanh_fast(v[r]);
            }

            // drain this wave's LDS ops (reads, writes, bpermutes), then sync.
            // NO vmcnt drain: global stores stay in flight across steps.
            asm volatile("s_waitcnt lgkmcnt(0)" ::: "memory");
            __builtin_amdgcn_s_barrier();
            asm volatile("" ::: "memory");
        }
    }
}

// ---------------------------------------------------------------------------
// K3: q = enc@Wq (f32) ; kT = enc@Wk + ba, stored transposed [b][h][s]
// ---------------------------------------------------------------------------
__global__ void k_qk(const _Float16* __restrict__ enc16, const float* __restrict__ Wa,
                     const float* __restrict__ ba, float* __restrict__ q,
                     float* __restrict__ kT) {
    int r0 = blockIdx.x * 8;
    int j = threadIdx.x;
    __shared__ float es[8][H];
#pragma unroll
    for (int r = 0; r < 8; ++r) es[r][j] = (float)enc16[(r0 + r) * H + j];
    __syncthreads();
    float aq[8] = {0, 0, 0, 0, 0, 0, 0, 0};
    float ak[8] = {0, 0, 0, 0, 0, 0, 0, 0};
    for (int i = 0; i < H; ++i) {
        float wq = Wa[i * H + j];
        float wk = Wa[(H + i) * H + j];
#pragma unroll
        for (int r = 0; r < 8; ++r) { aq[r] += es[r][i] * wq; ak[r] += es[r][i] * wk; }
    }
    float bav = ba[j];
#pragma unroll
    for (int r = 0; r < 8; ++r) {
        int row = r0 + r;
        int b = row >> 9, t = row & (S - 1);
        q[row * H + j] = aq[r];
        kT[((b * H + j) << 9) + t] = ak[r] + bav;
    }
}

// ---------------------------------------------------------------------------
// K4: fused scores -> softmax -> ctx for one (b,t) per block.
// ---------------------------------------------------------------------------
__global__ void k_attn(const float* __restrict__ q, const float* __restrict__ kT,
                       const _Float16* __restrict__ enc16, const float* __restrict__ va,
                       __hip_bfloat16* __restrict__ Abf) {
    int bt = blockIdx.x;
    int b = bt >> 9, t = bt & (S - 1);
    int tid = threadIdx.x;
    if (t == 0) {
        float e = (float)enc16[(b * S) * H + tid];
        Abf[bt * H + tid] = __float2bfloat16(2.0f * e);
        return;
    }
    __shared__ float qs[H], vas[H], part[4][S], wgt[S], red[8];
    qs[tid] = q[bt * H + tid];
    vas[tid] = va[tid];
    __syncthreads();

    int sl = tid & 63, g = tid >> 6;
    int nchunk = (t + 63) >> 6;
    const float* kTb = kT + ((size_t)(b * H) << 9);
    for (int c = 0; c < nchunk; ++c) {
        int s = c * 64 + sl;
        float p = 0.f;
        if (s < t) {
            int hb = g * 64;
            for (int i = 0; i < 64; ++i) {
                int h = hb + i;
                p += vas[h] * tanh_fast(qs[h] + kTb[(h << 9) + s]);
            }
        }
        part[g][s] = p;
    }
    __syncthreads();

    float m = -1e30f;
    for (int s = tid; s < t; s += 256) {
        float sc = part[0][s] + part[1][s] + part[2][s] + part[3][s];
        wgt[s] = sc;
        m = fmaxf(m, sc);
    }
#pragma unroll
    for (int off = 32; off; off >>= 1) m = fmaxf(m, __shfl_xor(m, off));
    if ((tid & 63) == 0) red[g] = m;
    __syncthreads();
    m = fmaxf(fmaxf(red[0], red[1]), fmaxf(red[2], red[3]));
    float ssum = 0.f;
    for (int s = tid; s < t; s += 256) {
        float e = exp2f((wgt[s] - m) * 1.4426950408889634f);
        wgt[s] = e;
        ssum += e;
    }
#pragma unroll
    for (int off = 32; off; off >>= 1) ssum += __shfl_xor(ssum, off);
    if ((tid & 63) == 0) red[4 + g] = ssum;
    __syncthreads();
    float inv = 1.0f / (red[4] + red[5] + red[6] + red[7]);

    float ctx = 0.f;
    const _Float16* eb = enc16 + (size_t)(b * S) * H + tid;
    for (int s = 0; s < t; ++s) ctx += wgt[s] * (float)eb[s * H];
    float et = (float)enc16[(b * S + t) * H + tid];
    Abf[bt * H + tid] = __float2bfloat16(ctx * inv + et);
}

// ---------------------------------------------------------------------------
// K5: out = A(2048x256 bf16) @ WoT^T(256x32000 bf16) + bo  -> f32
// ---------------------------------------------------------------------------
__global__ __launch_bounds__(256) void k_out(const __hip_bfloat16* __restrict__ Abf,
                                             const __hip_bfloat16* __restrict__ WoT,
                                             const float* __restrict__ bo,
                                             float* __restrict__ out) {
    int tid = threadIdx.x;
    int wv = tid >> 6, l = tid & 63;
    int mw = wv >> 1, nw = wv & 1;
    int lg = l >> 4, ll = l & 15;
    int m0 = blockIdx.y * 128 + mw * 64;
    int n0 = blockIdx.x * 128 + nw * 64;
    const short* Ap = (const short*)Abf;
    const short* Bp = (const short*)WoT;

    f32x4 acc[4][4];
#pragma unroll
    for (int mt = 0; mt < 4; ++mt)
#pragma unroll
        for (int nt = 0; nt < 4; ++nt) { f32x4 z; z[0]=0.f; z[1]=0.f; z[2]=0.f; z[3]=0.f; acc[mt][nt] = z; }

#pragma unroll
    for (int kk = 0; kk < 8; ++kk) {
        int k = kk * 32 + lg * 8;
        s16x8 a[4], bf[4];
#pragma unroll
        for (int mt = 0; mt < 4; ++mt)
            a[mt] = *(const s16x8*)&Ap[(m0 + mt * 16 + ll) * H + k];
#pragma unroll
        for (int nt = 0; nt < 4; ++nt)
            bf[nt] = *(const s16x8*)&Bp[(size_t)(n0 + nt * 16 + ll) * H + k];
#pragma unroll
        for (int mt = 0; mt < 4; ++mt)
#pragma unroll
            for (int nt = 0; nt < 4; ++nt)
                acc[mt][nt] = __builtin_amdgcn_mfma_f32_16x16x32_bf16(a[mt], bf[nt], acc[mt][nt], 0, 0, 0);
    }

#pragma unroll
    for (int nt = 0; nt < 4; ++nt) {
        int n = n0 + nt * 16 + ll;
        float bov = bo[n];
#pragma unroll
        for (int mt = 0; mt < 4; ++mt) {
#pragma unroll
            for (int r = 0; r < 4; ++r) {
                int mrow = m0 + mt * 16 + lg * 4 + r;
                out[(size_t)mrow * VOCAB + n] = acc[mt][nt][r] + bov;
            }
        }
    }
}

// ---------------------------------------------------------------------------
extern "C" void kernel_launch(void* const* d_in, const int* in_sizes, int n_in,
                              void* d_out, int out_size, void* d_ws, size_t ws_size,
                              hipStream_t stream) {
    const int*   x     = (const int*)d_in[0];
    const float* embed = (const float*)d_in[1];
    const float* Wi    = (const float*)d_in[2];
    const float* bi    = (const float*)d_in[3];
    const float* Wh    = (const float*)d_in[4];
    const float* bh    = (const float*)d_in[5];
    const float* Wa    = (const float*)d_in[6];
    const float* ba    = (const float*)d_in[7];
    const float* va    = (const float*)d_in[8];
    const float* Wo    = (const float*)d_in[9];
    const float* bo    = (const float*)d_in[10];
    float* out = (float*)d_out;

    char* wsb = (char*)d_ws;
    float*          Ew    = (float*)(wsb);                     //  2 MB
    _Float16*       enc16 = (_Float16*)(wsb + (2 << 20));      //  1 MB
    float*          q     = (float*)(wsb + (3 << 20));         //  2 MB
    float*          kT    = (float*)(wsb + (5 << 20));         //  2 MB
    __hip_bfloat16* Abf   = (__hip_bfloat16*)(wsb + (7 << 20));//  1 MB
    __hip_bfloat16* WoT   = (__hip_bfloat16*)(wsb + (8 << 20));// 16 MB
    float* out_tail = out + (size_t)B * S * VOCAB;

    hipLaunchKernelGGL(k_wot,   dim3(VOCAB / 64, 4), dim3(256), 0, stream, Wo, WoT);
    hipLaunchKernelGGL(k_eprep, dim3(S),             dim3(256), 0, stream, x, embed, Wi, bi, bh, Ew);
    // grid=256: block 0 real + writer; blocks 1-255 identical compute as
    // DVFS/clock pad (no global stores). See k_rnn comment.
    hipLaunchKernelGGL(k_rnn,   dim3(256),           dim3(256), 0, stream, Ew, Wh, enc16, out_tail);
    hipLaunchKernelGGL(k_qk,    dim3(B * S / 8),     dim3(256), 0, stream, enc16, Wa, ba, q, kT);
    hipLaunchKernelGGL(k_attn,  dim3(B * S),         dim3(256), 0, stream, q, kT, enc16, va, Abf);
    hipLaunchKernelGGL(k_out,   dim3(VOCAB / 128, (B * S) / 128), dim3(256), 0, stream, Abf, WoT, bo, out);
}

// Round 6
// 683.226 us; speedup vs baseline: 1.1741x; 1.1741x over previous
//
#include <hip/hip_runtime.h>
#include <hip/hip_bf16.h>
#include <hip/hip_fp16.h>

#define VOCAB 32000
#define H 256
#define B 4
#define S 512

typedef _Float16 f16x8 __attribute__((ext_vector_type(8)));
typedef short s16x8 __attribute__((ext_vector_type(8)));
typedef float f32x4 __attribute__((ext_vector_type(4)));

__device__ __forceinline__ float tanh_fast(float x) {
    float e = exp2f(x * 2.885390081777927f);   // exp(2x)
    return 1.0f - 2.0f * __builtin_amdgcn_rcpf(e + 1.0f);
}

// Fragment-major index for a bf16 matrix consumed as an MFMA operand:
// lane l of tile `row>>4` needs M[row = tile*16 + (l&15)][k = kk*32 + (l>>4)*8 + e].
// Stored so that a fragment load is base + lane*16B (fully coalesced).
__device__ __forceinline__ size_t fragIdx(int row, int h) {
    return ((size_t)((((row >> 4) * 8 + (h >> 5)) * 64) + ((h >> 3) & 3) * 16 + (row & 15)) << 3)
           + (h & 7);   // ushort units
}

// ---------------------------------------------------------------------------
// K0: Wo (256 x 32000) f32 -> WoTF: fragment-major bf16 (n-tiles x kk x lane x e)
// One block per 64 output rows (n), full K=256 staged in LDS.
// ---------------------------------------------------------------------------
__global__ __launch_bounds__(256) void k_wot(const float* __restrict__ Wo,
                                             ushort* __restrict__ WoTF) {
    __shared__ float tile[256][65];
    int n0 = blockIdx.x * 64;
    int tx = threadIdx.x & 63, ty = threadIdx.x >> 6;
#pragma unroll
    for (int i = 0; i < 64; ++i) {
        int k = i * 4 + ty;
        tile[k][tx] = Wo[(size_t)k * VOCAB + n0 + tx];
    }
    __syncthreads();
#pragma unroll
    for (int r = 0; r < 8; ++r) {
        int lin = threadIdx.x + 256 * r;           // unit id within block
        int ll = lin & 15, lg = (lin >> 4) & 3, kk = (lin >> 6) & 7, nt = lin >> 9;
        int n = nt * 16 + ll;
        s16x8 v;
#pragma unroll
        for (int e = 0; e < 8; ++e) {
            __hip_bfloat16 b = __float2bfloat16(tile[kk * 32 + lg * 8 + e][n]);
            v[e] = *(short*)&b;
        }
        size_t unit = (size_t)(((n0 >> 4) + nt) * 8 + kk) * 64 + lg * 16 + ll;
        *(s16x8*)&WoTF[unit * 8] = v;
    }
}

// ---------------------------------------------------------------------------
// K1: Ew[t][j][b] = sum_i embed[x[b][t]][i] * Wi[i][j] + bi[j] + bh[j]   (f32)
// ---------------------------------------------------------------------------
__global__ void k_eprep(const int* __restrict__ x, const float* __restrict__ embed,
                        const float* __restrict__ Wi, const float* __restrict__ bi,
                        const float* __restrict__ bh, float* __restrict__ Ew) {
    int t = blockIdx.x, j = threadIdx.x;
    __shared__ float es[B][H];
    __shared__ int xs[B];
    if (j < B) xs[j] = x[j * S + t];
    __syncthreads();
    for (int b = 0; b < B; ++b) es[b][j] = embed[(size_t)xs[b] * H + j];
    float bias = bi[j] + bh[j];
    float a0 = bias, a1 = bias, a2 = bias, a3 = bias;
    __syncthreads();
    for (int i = 0; i < H; ++i) {
        float w = Wi[i * H + j];
        a0 += es[0][i] * w; a1 += es[1][i] * w;
        a2 += es[2][i] * w; a3 += es[3][i] * w;
    }
    f32x4 v; v[0] = a0; v[1] = a1; v[2] = a2; v[3] = a3;
    *(f32x4*)&Ew[(t * H + j) * 4] = v;
}

// ---------------------------------------------------------------------------
// K2: serial RNN scan — EXACT R3 config (371us best): grid=1, 4 waves,
// pitch-258 LDS (0 bank conflicts), shfl redistribute, immediate stores,
// depth-2 Ew prefetch, 1 barrier/step. R4 delayed-store and R5 DVFS-pad
// both REVERTED (regressions +31us / +93us).
// ---------------------------------------------------------------------------
__global__ __launch_bounds__(256, 1) void k_rnn(const float* __restrict__ Ew,
                                                const float* __restrict__ Wh,
                                                _Float16* __restrict__ enc16,
                                                float* __restrict__ out_tail) {
    const int tid = threadIdx.x;
    const int w = tid >> 6;
    const int l = tid & 63;
    const int lg = l >> 4;
    const int ll = l & 15;

    __shared__ _Float16 hbuf[2][4][258];
    for (int idx = tid; idx < 2 * 4 * 258; idx += 256) (&hbuf[0][0][0])[idx] = (_Float16)0.f;

    f16x8 Bf[4][8];
#pragma unroll
    for (int nt = 0; nt < 4; ++nt) {
        int col = w * 64 + nt * 16 + ll;
#pragma unroll
        for (int kk = 0; kk < 8; ++kk) {
            int kb = kk * 32 + lg * 8;
            f16x8 v;
#pragma unroll
            for (int e = 0; e < 8; ++e) v[e] = (_Float16)Wh[(kb + e) * H + col];
            Bf[nt][kk] = v;
        }
    }
    __syncthreads();

    f32x4 eacc[2][4];
#pragma unroll
    for (int d = 0; d < 2; ++d)
#pragma unroll
        for (int nt = 0; nt < 4; ++nt) {
            int j = w * 64 + nt * 16 + ll;
            eacc[d][nt] = *(const f32x4*)&Ew[(d * H + j) * 4];
        }

    const int jcol = w * 64 + lg * 16 + ll;

    for (int t0 = 0; t0 < S; t0 += 2) {
#pragma unroll
        for (int u = 0; u < 2; ++u) {
            const int t = t0 + u;
            const int cur = u, nxt = u ^ 1;

            f16x8 Af[8];
#pragma unroll
            for (int kk = 0; kk < 8; ++kk)
                Af[kk] = *(const f16x8*)&hbuf[cur][l & 3][kk * 32 + lg * 8];

            f32x4 acc[4];
#pragma unroll
            for (int nt = 0; nt < 4; ++nt) acc[nt] = eacc[u][nt];

            {
                int tp = (t + 2 < S) ? t + 2 : S - 1;
#pragma unroll
                for (int nt = 0; nt < 4; ++nt) {
                    int j = w * 64 + nt * 16 + ll;
                    eacc[u][nt] = *(const f32x4*)&Ew[(tp * H + j) * 4];
                }
            }

#pragma unroll
            for (int kk = 0; kk < 8; ++kk)
#pragma unroll
                for (int nt = 0; nt < 4; ++nt)
                    acc[nt] = __builtin_amdgcn_mfma_f32_16x16x32_f16(Af[kk], Bf[nt][kk], acc[nt], 0, 0, 0);

            float v[4];
#pragma unroll
            for (int nt = 0; nt < 4; ++nt)
#pragma unroll
                for (int r = 0; r < 4; ++r) {
                    float tv = __shfl(acc[nt][r], ll);
                    if (lg == nt) v[r] = tv;
                }

            float hv[4];
#pragma unroll
            for (int r = 0; r < 4; ++r) hv[r] = tanh_fast(v[r]);

#pragma unroll
            for (int r = 0; r < 4; ++r) {
                _Float16 h16 = (_Float16)hv[r];
                hbuf[nxt][r][jcol] = h16;
                enc16[(r * S + t) * H + jcol] = h16;   // fire-and-forget
            }
            if (t == S - 1) {
#pragma unroll
                for (int r = 0; r < 4; ++r) out_tail[r * H + jcol] = hv[r];
            }

            asm volatile("s_waitcnt lgkmcnt(0)" ::: "memory");
            __builtin_amdgcn_s_barrier();
            asm volatile("" ::: "memory");
        }
    }
}

// ---------------------------------------------------------------------------
// K3: q = enc@Wq (f32) ; kT = enc@Wk + ba, stored transposed [b][h][s]
// ---------------------------------------------------------------------------
__global__ void k_qk(const _Float16* __restrict__ enc16, const float* __restrict__ Wa,
                     const float* __restrict__ ba, float* __restrict__ q,
                     float* __restrict__ kT) {
    int r0 = blockIdx.x * 8;
    int j = threadIdx.x;
    __shared__ float es[8][H];
#pragma unroll
    for (int r = 0; r < 8; ++r) es[r][j] = (float)enc16[(r0 + r) * H + j];
    __syncthreads();
    float aq[8] = {0, 0, 0, 0, 0, 0, 0, 0};
    float ak[8] = {0, 0, 0, 0, 0, 0, 0, 0};
    for (int i = 0; i < H; ++i) {
        float wq = Wa[i * H + j];
        float wk = Wa[(H + i) * H + j];
#pragma unroll
        for (int r = 0; r < 8; ++r) { aq[r] += es[r][i] * wq; ak[r] += es[r][i] * wk; }
    }
    float bav = ba[j];
#pragma unroll
    for (int r = 0; r < 8; ++r) {
        int row = r0 + r;
        int b = row >> 9, t = row & (S - 1);
        q[row * H + j] = aq[r];
        kT[((b * H + j) << 9) + t] = ak[r] + bav;
    }
}

// ---------------------------------------------------------------------------
// K4: fused scores -> softmax -> ctx for one (b,t) per block.
// Writes A in FRAGMENT-MAJOR bf16 (AbfF) so k_out's loads coalesce.
// ---------------------------------------------------------------------------
__global__ void k_attn(const float* __restrict__ q, const float* __restrict__ kT,
                       const _Float16* __restrict__ enc16, const float* __restrict__ va,
                       ushort* __restrict__ AbfF) {
    int bt = blockIdx.x;
    int b = bt >> 9, t = bt & (S - 1);
    int tid = threadIdx.x;
    if (t == 0) {   // reference: ctx[:,0] = enc[:,0]  ->  A = 2*enc
        float e = (float)enc16[(b * S) * H + tid];
        __hip_bfloat16 bf = __float2bfloat16(2.0f * e);
        AbfF[fragIdx(bt, tid)] = *(ushort*)&bf;
        return;
    }
    __shared__ float qs[H], vas[H], part[4][S], wgt[S], red[8];
    qs[tid] = q[bt * H + tid];
    vas[tid] = va[tid];
    __syncthreads();

    int sl = tid & 63, g = tid >> 6;
    int nchunk = (t + 63) >> 6;
    const float* kTb = kT + ((size_t)(b * H) << 9);
    for (int c = 0; c < nchunk; ++c) {
        int s = c * 64 + sl;
        float p = 0.f;
        if (s < t) {
            int hb = g * 64;
            for (int i = 0; i < 64; ++i) {
                int h = hb + i;
                p += vas[h] * tanh_fast(qs[h] + kTb[(h << 9) + s]);
            }
        }
        part[g][s] = p;
    }
    __syncthreads();

    float m = -1e30f;
    for (int s = tid; s < t; s += 256) {
        float sc = part[0][s] + part[1][s] + part[2][s] + part[3][s];
        wgt[s] = sc;
        m = fmaxf(m, sc);
    }
#pragma unroll
    for (int off = 32; off; off >>= 1) m = fmaxf(m, __shfl_xor(m, off));
    if ((tid & 63) == 0) red[g] = m;
    __syncthreads();
    m = fmaxf(fmaxf(red[0], red[1]), fmaxf(red[2], red[3]));
    float ssum = 0.f;
    for (int s = tid; s < t; s += 256) {
        float e = exp2f((wgt[s] - m) * 1.4426950408889634f);
        wgt[s] = e;
        ssum += e;
    }
#pragma unroll
    for (int off = 32; off; off >>= 1) ssum += __shfl_xor(ssum, off);
    if ((tid & 63) == 0) red[4 + g] = ssum;
    __syncthreads();
    float inv = 1.0f / (red[4] + red[5] + red[6] + red[7]);

    float ctx = 0.f;
    const _Float16* eb = enc16 + (size_t)(b * S) * H + tid;
    for (int s = 0; s < t; ++s) ctx += wgt[s] * (float)eb[s * H];
    float et = (float)enc16[(b * S + t) * H + tid];
    __hip_bfloat16 bf = __float2bfloat16(ctx * inv + et);
    AbfF[fragIdx(bt, tid)] = *(ushort*)&bf;
}

// ---------------------------------------------------------------------------
// K5: out = A(2048x256 bf16) @ WoT^T + bo -> f32. Block tile 128x128, 4 waves.
// v2: both operands FRAGMENT-MAJOR -> every load is base + lane*16B
// (contiguous 1KB/instr). R5 theory: the old per-row loads were 64-line
// scatters (stride 512B), 4x L2 overfetch + slow address processing.
// ---------------------------------------------------------------------------
__global__ __launch_bounds__(256) void k_out(const ushort* __restrict__ AbfF,
                                             const ushort* __restrict__ WoTF,
                                             const float* __restrict__ bo,
                                             float* __restrict__ out) {
    int tid = threadIdx.x;
    int wv = tid >> 6, l = tid & 63;
    int mw = wv >> 1, nw = wv & 1;
    int lg = l >> 4, ll = l & 15;
    int m0 = blockIdx.y * 128 + mw * 64;
    int n0 = blockIdx.x * 128 + nw * 64;

    f32x4 acc[4][4];
#pragma unroll
    for (int mt = 0; mt < 4; ++mt)
#pragma unroll
        for (int nt = 0; nt < 4; ++nt) { f32x4 z; z[0]=0.f; z[1]=0.f; z[2]=0.f; z[3]=0.f; acc[mt][nt] = z; }

#pragma unroll
    for (int kk = 0; kk < 8; ++kk) {
        s16x8 a[4], bf[4];
#pragma unroll
        for (int mt = 0; mt < 4; ++mt)
            a[mt] = *(const s16x8*)&AbfF[((size_t)(((m0 >> 4) + mt) * 8 + kk) * 64 + l) * 8];
#pragma unroll
        for (int nt = 0; nt < 4; ++nt)
            bf[nt] = *(const s16x8*)&WoTF[((size_t)(((n0 >> 4) + nt) * 8 + kk) * 64 + l) * 8];
#pragma unroll
        for (int mt = 0; mt < 4; ++mt)
#pragma unroll
            for (int nt = 0; nt < 4; ++nt)
                acc[mt][nt] = __builtin_amdgcn_mfma_f32_16x16x32_bf16(a[mt], bf[nt], acc[mt][nt], 0, 0, 0);
    }

#pragma unroll
    for (int nt = 0; nt < 4; ++nt) {
        int n = n0 + nt * 16 + ll;
        float bov = bo[n];
#pragma unroll
        for (int mt = 0; mt < 4; ++mt) {
#pragma unroll
            for (int r = 0; r < 4; ++r) {
                int mrow = m0 + mt * 16 + lg * 4 + r;
                out[(size_t)mrow * VOCAB + n] = acc[mt][nt][r] + bov;
            }
        }
    }
}

// ---------------------------------------------------------------------------
extern "C" void kernel_launch(void* const* d_in, const int* in_sizes, int n_in,
                              void* d_out, int out_size, void* d_ws, size_t ws_size,
                              hipStream_t stream) {
    const int*   x     = (const int*)d_in[0];
    const float* embed = (const float*)d_in[1];
    const float* Wi    = (const float*)d_in[2];
    const float* bi    = (const float*)d_in[3];
    const float* Wh    = (const float*)d_in[4];
    const float* bh    = (const float*)d_in[5];
    const float* Wa    = (const float*)d_in[6];
    const float* ba    = (const float*)d_in[7];
    const float* va    = (const float*)d_in[8];
    const float* Wo    = (const float*)d_in[9];
    const float* bo    = (const float*)d_in[10];
    float* out = (float*)d_out;

    char* wsb = (char*)d_ws;
    float*    Ew    = (float*)(wsb);                  //  2 MB
    _Float16* enc16 = (_Float16*)(wsb + (2 << 20));   //  1 MB
    float*    q     = (float*)(wsb + (3 << 20));      //  2 MB
    float*    kT    = (float*)(wsb + (5 << 20));      //  2 MB
    ushort*   AbfF  = (ushort*)(wsb + (7 << 20));     //  1 MB  fragment-major A
    ushort*   WoTF  = (ushort*)(wsb + (8 << 20));     // 16 MB  fragment-major B
    float* out_tail = out + (size_t)B * S * VOCAB;

    hipLaunchKernelGGL(k_wot,   dim3(VOCAB / 64),     dim3(256), 0, stream, Wo, WoTF);
    hipLaunchKernelGGL(k_eprep, dim3(S),              dim3(256), 0, stream, x, embed, Wi, bi, bh, Ew);
    hipLaunchKernelGGL(k_rnn,   dim3(1),              dim3(256), 0, stream, Ew, Wh, enc16, out_tail);
    hipLaunchKernelGGL(k_qk,    dim3(B * S / 8),      dim3(256), 0, stream, enc16, Wa, ba, q, kT);
    hipLaunchKernelGGL(k_attn,  dim3(B * S),          dim3(256), 0, stream, q, kT, enc16, va, AbfF);
    hipLaunchKernelGGL(k_out,   dim3(VOCAB / 128, (B * S) / 128), dim3(256), 0, stream, AbfF, WoTF, bo, out);
}

// Round 7
// 601.893 us; speedup vs baseline: 1.3328x; 1.1351x over previous
//
#include <hip/hip_runtime.h>
#include <hip/hip_bf16.h>
#include <hip/hip_fp16.h>

#define VOCAB 32000
#define H 256
#define B 4
#define S 512

typedef _Float16 f16x8 __attribute__((ext_vector_type(8)));
typedef short s16x8 __attribute__((ext_vector_type(8)));
typedef float f32x4 __attribute__((ext_vector_type(4)));

__device__ __forceinline__ float tanh_fast(float x) {
    float e = exp2f(x * 2.885390081777927f);   // exp(2x)
    return 1.0f - 2.0f * __builtin_amdgcn_rcpf(e + 1.0f);
}

// Fragment-major index (A-operand view) for a bf16/f16 matrix row x k:
// unit = ((row>>4)*KK + (k>>5))*64 + ((k>>3)&3)*16 + (row&15), elem = k&7.
__device__ __forceinline__ size_t fragIdx(int row, int h) {   // KK=8 (K=256)
    return ((size_t)((((row >> 4) * 8 + (h >> 5)) * 64) + ((h >> 3) & 3) * 16 + (row & 15)) << 3)
           + (h & 7);
}

// ---------------------------------------------------------------------------
// K0: Wo (256 x 32000) f32 -> WoTF fragment-major bf16
// ---------------------------------------------------------------------------
__global__ __launch_bounds__(256) void k_wot(const float* __restrict__ Wo,
                                             ushort* __restrict__ WoTF) {
    __shared__ float tile[256][65];
    int n0 = blockIdx.x * 64;
    int tx = threadIdx.x & 63, ty = threadIdx.x >> 6;
#pragma unroll
    for (int i = 0; i < 64; ++i) {
        int k = i * 4 + ty;
        tile[k][tx] = Wo[(size_t)k * VOCAB + n0 + tx];
    }
    __syncthreads();
#pragma unroll
    for (int r = 0; r < 8; ++r) {
        int lin = threadIdx.x + 256 * r;
        int ll = lin & 15, lg = (lin >> 4) & 3, kk = (lin >> 6) & 7, nt = lin >> 9;
        int n = nt * 16 + ll;
        s16x8 v;
#pragma unroll
        for (int e = 0; e < 8; ++e) {
            __hip_bfloat16 b = __float2bfloat16(tile[kk * 32 + lg * 8 + e][n]);
            v[e] = *(short*)&b;
        }
        size_t unit = (size_t)(((n0 >> 4) + nt) * 8 + kk) * 64 + lg * 16 + ll;
        *(s16x8*)&WoTF[unit * 8] = v;
    }
}

// ---------------------------------------------------------------------------
// K1: Ew[t][j][b] = emb@Wi + bi + bh   (f32, [t][j][b4])
// ---------------------------------------------------------------------------
__global__ void k_eprep(const int* __restrict__ x, const float* __restrict__ embed,
                        const float* __restrict__ Wi, const float* __restrict__ bi,
                        const float* __restrict__ bh, float* __restrict__ Ew) {
    int t = blockIdx.x, j = threadIdx.x;
    __shared__ float es[B][H];
    __shared__ int xs[B];
    if (j < B) xs[j] = x[j * S + t];
    __syncthreads();
    for (int b = 0; b < B; ++b) es[b][j] = embed[(size_t)xs[b] * H + j];
    float bias = bi[j] + bh[j];
    float a0 = bias, a1 = bias, a2 = bias, a3 = bias;
    __syncthreads();
    for (int i = 0; i < H; ++i) {
        float w = Wi[i * H + j];
        a0 += es[0][i] * w; a1 += es[1][i] * w;
        a2 += es[2][i] * w; a3 += es[3][i] * w;
    }
    f32x4 v; v[0] = a0; v[1] = a1; v[2] = a2; v[3] = a3;
    *(f32x4*)&Ew[(t * H + j) * 4] = v;
}

// ---------------------------------------------------------------------------
// K2 v6: serial RNN scan. R3 base (pitch-258, depth-2 prefetch, 1 barrier) +
// NEW: shfl redistribute removed. Since eacc is identical across lane-groups
// and A rows 4-15 replicate the batches (hbuf[l&3]), D rows 4-15 are valid
// replicas -> lane (lg,ll) already holds h_next[r][w*64+lg*16+ll] as
// acc[lg][r]. The 16 ds_bpermutes were an identity permutation; replace with
// a static exec-masked select (saves ~100cy/step of issue+latency).
// ---------------------------------------------------------------------------
__global__ __launch_bounds__(256, 1) void k_rnn(const float* __restrict__ Ew,
                                                const float* __restrict__ Wh,
                                                _Float16* __restrict__ enc16,
                                                float* __restrict__ out_tail) {
    const int tid = threadIdx.x;
    const int w = tid >> 6;
    const int l = tid & 63;
    const int lg = l >> 4;
    const int ll = l & 15;

    __shared__ _Float16 hbuf[2][4][258];
    for (int idx = tid; idx < 2 * 4 * 258; idx += 256) (&hbuf[0][0][0])[idx] = (_Float16)0.f;

    f16x8 Bf[4][8];
#pragma unroll
    for (int nt = 0; nt < 4; ++nt) {
        int col = w * 64 + nt * 16 + ll;
#pragma unroll
        for (int kk = 0; kk < 8; ++kk) {
            int kb = kk * 32 + lg * 8;
            f16x8 v;
#pragma unroll
            for (int e = 0; e < 8; ++e) v[e] = (_Float16)Wh[(kb + e) * H + col];
            Bf[nt][kk] = v;
        }
    }
    __syncthreads();

    f32x4 eacc[2][4];
#pragma unroll
    for (int d = 0; d < 2; ++d)
#pragma unroll
        for (int nt = 0; nt < 4; ++nt) {
            int j = w * 64 + nt * 16 + ll;
            eacc[d][nt] = *(const f32x4*)&Ew[(d * H + j) * 4];
        }

    const int jcol = w * 64 + lg * 16 + ll;

    for (int t0 = 0; t0 < S; t0 += 2) {
#pragma unroll
        for (int u = 0; u < 2; ++u) {
            const int t = t0 + u;
            const int cur = u, nxt = u ^ 1;

            f16x8 Af[8];
#pragma unroll
            for (int kk = 0; kk < 8; ++kk)
                Af[kk] = *(const f16x8*)&hbuf[cur][l & 3][kk * 32 + lg * 8];

            f32x4 acc[4];
#pragma unroll
            for (int nt = 0; nt < 4; ++nt) acc[nt] = eacc[u][nt];

            {
                int tp = (t + 2 < S) ? t + 2 : S - 1;
#pragma unroll
                for (int nt = 0; nt < 4; ++nt) {
                    int j = w * 64 + nt * 16 + ll;
                    eacc[u][nt] = *(const f32x4*)&Ew[(tp * H + j) * 4];
                }
            }

#pragma unroll
            for (int kk = 0; kk < 8; ++kk)
#pragma unroll
                for (int nt = 0; nt < 4; ++nt)
                    acc[nt] = __builtin_amdgcn_mfma_f32_16x16x32_f16(Af[kk], Bf[nt][kk], acc[nt], 0, 0, 0);

            // static select: v[r] = acc[lg][r]  (no cross-lane traffic)
            float v[4];
#pragma unroll
            for (int nt = 0; nt < 4; ++nt) {
                if (lg == nt) {
#pragma unroll
                    for (int r = 0; r < 4; ++r) v[r] = acc[nt][r];
                }
            }

            float hv[4];
#pragma unroll
            for (int r = 0; r < 4; ++r) hv[r] = tanh_fast(v[r]);

#pragma unroll
            for (int r = 0; r < 4; ++r) {
                _Float16 h16 = (_Float16)hv[r];
                hbuf[nxt][r][jcol] = h16;
                enc16[(r * S + t) * H + jcol] = h16;   // fire-and-forget
            }
            if (t == S - 1) {
#pragma unroll
                for (int r = 0; r < 4; ++r) out_tail[r * H + jcol] = hv[r];
            }

            asm volatile("s_waitcnt lgkmcnt(0)" ::: "memory");
            __builtin_amdgcn_s_barrier();
            asm volatile("" ::: "memory");
        }
    }
}

// ---------------------------------------------------------------------------
// K3: q = enc@Wq ; kT = enc@Wk + ba ([b][h][s]); ALSO emits encF:
// enc in B-fragment-major f16 (n=h tiles x kk(s) x lane x e) for k_ctx.
// ---------------------------------------------------------------------------
__global__ void k_qk(const _Float16* __restrict__ enc16, const float* __restrict__ Wa,
                     const float* __restrict__ ba, float* __restrict__ q,
                     float* __restrict__ kT, ushort* __restrict__ encF) {
    int r0 = blockIdx.x * 8;
    int j = threadIdx.x;
    __shared__ float es[8][H];
#pragma unroll
    for (int r = 0; r < 8; ++r) es[r][j] = (float)enc16[(r0 + r) * H + j];
    __syncthreads();
    float aq[8] = {0, 0, 0, 0, 0, 0, 0, 0};
    float ak[8] = {0, 0, 0, 0, 0, 0, 0, 0};
    for (int i = 0; i < H; ++i) {
        float wq = Wa[i * H + j];
        float wk = Wa[(H + i) * H + j];
#pragma unroll
        for (int r = 0; r < 8; ++r) { aq[r] += es[r][i] * wq; ak[r] += es[r][i] * wk; }
    }
    float bav = ba[j];
#pragma unroll
    for (int r = 0; r < 8; ++r) {
        int row = r0 + r;
        int b = row >> 9, t = row & (S - 1);
        q[row * H + j] = aq[r];
        kT[((b * H + j) << 9) + t] = ak[r] + bav;
        // encF[b][h-tile][kk(s)][lane][e]:  n=j, k=s=t
        _Float16 ev = (_Float16)es[r][j];
        size_t unit = (size_t)((b * 16 + (j >> 4)) * 16 + (t >> 5)) * 64 + ((t >> 3) & 3) * 16 + (j & 15);
        encF[unit * 8 + (t & 7)] = *(ushort*)&ev;
    }
}

// ---------------------------------------------------------------------------
// K4: scores -> softmax; writes NORMALIZED f16 weights in A-fragment-major
// (row=t, k=s, causal zeros; t==0 row = delta at s=0, which also implements
// the reference's ctx[:,0]=enc[:,0] override). ctx GEMM moved to k_ctx.
// ---------------------------------------------------------------------------
__global__ void k_attn(const float* __restrict__ q, const float* __restrict__ kT,
                       const float* __restrict__ va, ushort* __restrict__ WgtF) {
    int bt = blockIdx.x;
    int b = bt >> 9, t = bt & (S - 1);
    int tid = threadIdx.x;
    if (t == 0) {
        for (int ss = tid; ss < S; ss += 256) {
            _Float16 hw = (_Float16)((ss == 0) ? 1.f : 0.f);
            size_t unit = (size_t)((b * 32 + (t >> 4)) * 16 + (ss >> 5)) * 64 + ((ss >> 3) & 3) * 16 + (t & 15);
            WgtF[unit * 8 + (ss & 7)] = *(ushort*)&hw;
        }
        return;
    }
    __shared__ float qs[H], vas[H], part[4][S], wgt[S], red[8];
    qs[tid] = q[bt * H + tid];
    vas[tid] = va[tid];
    __syncthreads();

    int sl = tid & 63, g = tid >> 6;
    int nchunk = (t + 63) >> 6;
    const float* kTb = kT + ((size_t)(b * H) << 9);
    for (int c = 0; c < nchunk; ++c) {
        int s = c * 64 + sl;
        float p = 0.f;
        if (s < t) {
            int hb = g * 64;
            for (int i = 0; i < 64; ++i) {
                int h = hb + i;
                p += vas[h] * tanh_fast(qs[h] + kTb[(h << 9) + s]);
            }
        }
        part[g][s] = p;
    }
    __syncthreads();

    float m = -1e30f;
    for (int s = tid; s < t; s += 256) {
        float sc = part[0][s] + part[1][s] + part[2][s] + part[3][s];
        wgt[s] = sc;
        m = fmaxf(m, sc);
    }
#pragma unroll
    for (int off = 32; off; off >>= 1) m = fmaxf(m, __shfl_xor(m, off));
    if ((tid & 63) == 0) red[g] = m;
    __syncthreads();
    m = fmaxf(fmaxf(red[0], red[1]), fmaxf(red[2], red[3]));
    float ssum = 0.f;
    for (int s = tid; s < t; s += 256) {
        float e = exp2f((wgt[s] - m) * 1.4426950408889634f);
        wgt[s] = e;
        ssum += e;
    }
#pragma unroll
    for (int off = 32; off; off >>= 1) ssum += __shfl_xor(ssum, off);
    if ((tid & 63) == 0) red[4 + g] = ssum;
    __syncthreads();
    float inv = 1.0f / (red[4] + red[5] + red[6] + red[7]);

    for (int ss = tid; ss < S; ss += 256) {
        float wv = (ss < t) ? wgt[ss] * inv : 0.f;
        _Float16 hw = (_Float16)wv;
        size_t unit = (size_t)((b * 32 + (t >> 4)) * 16 + (ss >> 5)) * 64 + ((ss >> 3) & 3) * 16 + (t & 15);
        WgtF[unit * 8 + (ss & 7)] = *(ushort*)&hw;
    }
}

// ---------------------------------------------------------------------------
// K_CTX: ctx = Wgt(512x512 f16) @ enc(512x256 f16) per batch, + enc, -> AbfF.
// Block: 32 t-rows x full H; 4 waves, wave wv owns n-cols wv*64. 128 MFMA/wave.
// Replaces k_attn's O(t) serial per-thread ctx loop (avg 256 iters) with MFMA.
// ---------------------------------------------------------------------------
__global__ __launch_bounds__(256) void k_ctx(const ushort* __restrict__ WgtF,
                                             const ushort* __restrict__ encF,
                                             const _Float16* __restrict__ enc16,
                                             ushort* __restrict__ AbfF) {
    int b = blockIdx.y;
    int m0 = blockIdx.x * 32;
    int tid = threadIdx.x;
    int wv = tid >> 6, l = tid & 63;
    int lg = l >> 4, ll = l & 15;

    f32x4 acc[2][4];
#pragma unroll
    for (int mt = 0; mt < 2; ++mt)
#pragma unroll
        for (int nt = 0; nt < 4; ++nt) { f32x4 z; z[0]=0.f; z[1]=0.f; z[2]=0.f; z[3]=0.f; acc[mt][nt] = z; }

#pragma unroll
    for (int kk = 0; kk < 16; ++kk) {
        f16x8 a[2], bf[4];
#pragma unroll
        for (int mt = 0; mt < 2; ++mt)
            a[mt] = *(const f16x8*)&WgtF[((size_t)((b * 32 + (m0 >> 4) + mt) * 16 + kk) * 64 + l) * 8];
#pragma unroll
        for (int nt = 0; nt < 4; ++nt)
            bf[nt] = *(const f16x8*)&encF[((size_t)((b * 16 + wv * 4 + nt) * 16 + kk) * 64 + l) * 8];
#pragma unroll
        for (int mt = 0; mt < 2; ++mt)
#pragma unroll
            for (int nt = 0; nt < 4; ++nt)
                acc[mt][nt] = __builtin_amdgcn_mfma_f32_16x16x32_f16(a[mt], bf[nt], acc[mt][nt], 0, 0, 0);
    }

#pragma unroll
    for (int mt = 0; mt < 2; ++mt)
#pragma unroll
        for (int nt = 0; nt < 4; ++nt)
#pragma unroll
            for (int r = 0; r < 4; ++r) {
                int trow = m0 + mt * 16 + lg * 4 + r;
                int h = wv * 64 + nt * 16 + ll;
                float ev = (float)enc16[(size_t)(b * S + trow) * H + h];
                __hip_bfloat16 o = __float2bfloat16(acc[mt][nt][r] + ev);
                AbfF[fragIdx(b * S + trow, h)] = *(ushort*)&o;
            }
}

// ---------------------------------------------------------------------------
// K5: out = A @ WoT^T + bo. Fragment-major operands. Grid transposed (m
// fastest) so consecutive blocks share the 64KB B-panel; A (1MB) L2-resident.
// ---------------------------------------------------------------------------
__global__ __launch_bounds__(256) void k_out(const ushort* __restrict__ AbfF,
                                             const ushort* __restrict__ WoTF,
                                             const float* __restrict__ bo,
                                             float* __restrict__ out) {
    int tid = threadIdx.x;
    int wv = tid >> 6, l = tid & 63;
    int mw = wv >> 1, nw = wv & 1;
    int lg = l >> 4, ll = l & 15;
    int m0 = blockIdx.x * 128 + mw * 64;   // x: 16 m-blocks (fastest)
    int n0 = blockIdx.y * 128 + nw * 64;   // y: 250 n-blocks

    f32x4 acc[4][4];
#pragma unroll
    for (int mt = 0; mt < 4; ++mt)
#pragma unroll
        for (int nt = 0; nt < 4; ++nt) { f32x4 z; z[0]=0.f; z[1]=0.f; z[2]=0.f; z[3]=0.f; acc[mt][nt] = z; }

#pragma unroll
    for (int kk = 0; kk < 8; ++kk) {
        s16x8 a[4], bf[4];
#pragma unroll
        for (int mt = 0; mt < 4; ++mt)
            a[mt] = *(const s16x8*)&AbfF[((size_t)(((m0 >> 4) + mt) * 8 + kk) * 64 + l) * 8];
#pragma unroll
        for (int nt = 0; nt < 4; ++nt)
            bf[nt] = *(const s16x8*)&WoTF[((size_t)(((n0 >> 4) + nt) * 8 + kk) * 64 + l) * 8];
#pragma unroll
        for (int mt = 0; mt < 4; ++mt)
#pragma unroll
            for (int nt = 0; nt < 4; ++nt)
                acc[mt][nt] = __builtin_amdgcn_mfma_f32_16x16x32_bf16(a[mt], bf[nt], acc[mt][nt], 0, 0, 0);
    }

#pragma unroll
    for (int nt = 0; nt < 4; ++nt) {
        int n = n0 + nt * 16 + ll;
        float bov = bo[n];
#pragma unroll
        for (int mt = 0; mt < 4; ++mt) {
#pragma unroll
            for (int r = 0; r < 4; ++r) {
                int mrow = m0 + mt * 16 + lg * 4 + r;
                out[(size_t)mrow * VOCAB + n] = acc[mt][nt][r] + bov;
            }
        }
    }
}

// ---------------------------------------------------------------------------
extern "C" void kernel_launch(void* const* d_in, const int* in_sizes, int n_in,
                              void* d_out, int out_size, void* d_ws, size_t ws_size,
                              hipStream_t stream) {
    const int*   x     = (const int*)d_in[0];
    const float* embed = (const float*)d_in[1];
    const float* Wi    = (const float*)d_in[2];
    const float* bi    = (const float*)d_in[3];
    const float* Wh    = (const float*)d_in[4];
    const float* bh    = (const float*)d_in[5];
    const float* Wa    = (const float*)d_in[6];
    const float* ba    = (const float*)d_in[7];
    const float* va    = (const float*)d_in[8];
    const float* Wo    = (const float*)d_in[9];
    const float* bo    = (const float*)d_in[10];
    float* out = (float*)d_out;

    char* wsb = (char*)d_ws;
    float*    Ew    = (float*)(wsb);                  //  2 MB
    _Float16* enc16 = (_Float16*)(wsb + (2 << 20));   //  1 MB
    float*    q     = (float*)(wsb + (3 << 20));      //  2 MB
    float*    kT    = (float*)(wsb + (5 << 20));      //  2 MB
    ushort*   AbfF  = (ushort*)(wsb + (7 << 20));     //  1 MB  A fragment-major
    ushort*   WoTF  = (ushort*)(wsb + (8 << 20));     // 16 MB  B fragment-major
    ushort*   WgtF  = (ushort*)(wsb + (24 << 20));    //  2 MB  weights frag-major
    ushort*   encF  = (ushort*)(wsb + (26 << 20));    //  1 MB  enc B-frag-major
    float* out_tail = out + (size_t)B * S * VOCAB;

    hipLaunchKernelGGL(k_wot,   dim3(VOCAB / 64),     dim3(256), 0, stream, Wo, WoTF);
    hipLaunchKernelGGL(k_eprep, dim3(S),              dim3(256), 0, stream, x, embed, Wi, bi, bh, Ew);
    hipLaunchKernelGGL(k_rnn,   dim3(1),              dim3(256), 0, stream, Ew, Wh, enc16, out_tail);
    hipLaunchKernelGGL(k_qk,    dim3(B * S / 8),      dim3(256), 0, stream, enc16, Wa, ba, q, kT, encF);
    hipLaunchKernelGGL(k_attn,  dim3(B * S),          dim3(256), 0, stream, q, kT, va, WgtF);
    hipLaunchKernelGGL(k_ctx,   dim3(S / 32, B),      dim3(256), 0, stream, WgtF, encF, enc16, AbfF);
    hipLaunchKernelGGL(k_out,   dim3(16, VOCAB / 128), dim3(256), 0, stream, AbfF, WoTF, bo, out);
}